// Round 9
// baseline (56.358 us; speedup 1.0000x reference)
//
#include <hip/hip_runtime.h>
#include <hip/hip_bf16.h>

typedef __attribute__((ext_vector_type(4))) float f32x4;
typedef __attribute__((ext_vector_type(8))) short short8;

#define B_ 16
#define C_ 64
#define H_ 128
#define W_ 128
#define Z_ 128
#define HW_ (H_*W_)
#define IDXN (C_*C_*9)    // 36864 weight elements per sample
#define NT 18             // K=576 -> 18 MFMA k-steps of 32
#define WBYTES (NT*4*64*8*2)   // 73728 B of wfrag per sample
#define XBYTES (4*130*128)     // 66560 B of staged x rows

#define AS_GLOBAL(p) ((const __attribute__((address_space(1))) void*)(p))
#define AS_LDS(p)    ((__attribute__((address_space(3))) void*)(p))

__device__ __forceinline__ unsigned short f2bf(float f) {
  __hip_bfloat16 h = __float2bfloat16(f);
  return *reinterpret_cast<unsigned short*>(&h);
}

// ---------------- kernel 1: weight generation, pre-swizzled to MFMA fragment layout
__global__ __launch_bounds__(256) void wgen_k(
    const float* __restrict__ z, const float* __restrict__ gw,
    const float* __restrict__ gb, unsigned short* __restrict__ wfrag) {
  __shared__ __align__(16) float zs[B_*Z_];   // 8 KB
  int t = threadIdx.x;
#pragma unroll
  for (int i = 0; i < 8; ++i) zs[i*256 + t] = z[i*256 + t];
  __syncthreads();
  int lane = t & 63, bg = t >> 6;
  int b0 = bg*4;
  int idx0 = blockIdx.x*128 + lane;           // stream 0: idx0, stream 1: idx0+64
  float acc[4][2];
  float bv0 = gb[idx0], bv1 = gb[idx0 + 64];
#pragma unroll
  for (int bi = 0; bi < 4; ++bi) { acc[bi][0] = bv0; acc[bi][1] = bv1; }

  for (int z0 = 0; z0 < Z_; z0 += 4) {
    float ga[4], gbv[4];
#pragma unroll
    for (int zi = 0; zi < 4; ++zi) {
      ga[zi]  = gw[(size_t)(z0+zi)*IDXN + idx0];
      gbv[zi] = gw[(size_t)(z0+zi)*IDXN + idx0 + 64];
    }
#pragma unroll
    for (int bi = 0; bi < 4; ++bi) {
      f32x4 zq = *reinterpret_cast<const f32x4*>(&zs[(b0+bi)*Z_ + z0]);
      acc[bi][0] = fmaf(zq[0], ga[0], fmaf(zq[1], ga[1], fmaf(zq[2], ga[2], fmaf(zq[3], ga[3], acc[bi][0]))));
      acc[bi][1] = fmaf(zq[0], gbv[0], fmaf(zq[1], gbv[1], fmaf(zq[2], gbv[2], fmaf(zq[3], gbv[3], acc[bi][1]))));
    }
  }
#pragma unroll
  for (int ni = 0; ni < 2; ++ni) {
    int idx = idx0 + ni*64;
    int kw = idx % 3, r1 = idx/3;
    int kh = r1 % 3, r2 = r1/3;
    int ci = r2 & 63, co = r2 >> 6;
    int k = (kh*3 + kw)*C_ + ci;
    int ts = k >> 5, kin = k & 31;
    int lm = (co & 15) | ((kin >> 3) << 4);
    int j = kin & 7, m = co >> 4;
    int base = ((ts*4 + m)*64 + lm)*8 + j;
#pragma unroll
    for (int bi = 0; bi < 4; ++bi)
      wfrag[(size_t)(b0+bi)*(NT*4*64*8) + base] = f2bf(acc[bi][ni]);
  }
}

// ---------------- kernel 2 (fused): per-sample conv as MFMA implicit GEMM
// 2-row output block, 512 thr = 8 waves, 1 block/CU.
// ALL weights for the sample staged to LDS via global_load_lds (73728 B, linear layout)
// -> steady-state K-loop is PURE LDS + MFMA (no global ops): A/B test of the
//    "global weight stream latency" hypothesis.
// x LDS: xs[4 rows][130 cols][8 chunk-slots][16B]; slot s at col holds chunk s^(col&7).
// Wave v: row phr=v>>2, px half pw0=((v>>1)&1)*64, co half mt0=(v&1)*2 (R5-verified).
__global__ __launch_bounds__(512, 2) void conv_k(
    const float* __restrict__ x,
    const unsigned short* __restrict__ wfrag,
    float* __restrict__ out) {
  __shared__ __align__(16) unsigned char xs[XBYTES + WBYTES];   // 140288 B -> 1 block/CU
  unsigned char* wlds = xs + XBYTES;
  int orig = blockIdx.x;
  int blk = (orig & 7)*128 + (orig >> 3);   // bijective XCD swizzle: 1024 = 8*128
  int b = blk >> 6;
  int h0 = (blk & 63)*2;
  int tid = threadIdx.x;
  int v = tid >> 6, lane = tid & 63;

  // ---- stage ALL sample weights into LDS: 73728 B = 4608 x 16B chunks, 9 per thread
  {
    const unsigned char* wg = reinterpret_cast<const unsigned char*>(
        wfrag + (size_t)b*(NT*4*64*8));
#pragma unroll
    for (int i = 0; i < 9; ++i) {
      int cb = i*512 + v*64;                 // wave-uniform chunk base
      __builtin_amdgcn_global_load_lds(
          AS_GLOBAL(wg + ((size_t)(cb + lane))*16),
          AS_LDS(wlds + (size_t)cb*16), 16, 0, 0);
    }
  }

  // ---- stage 4 halo x rows (h0-1..h0+2); wave v stages (row v>>1, chunk-half v&1)
  {
    int r = v >> 1, hf = v & 1;
    int hh = h0 - 1 + r;
    bool hv = (hh >= 0) & (hh < H_);
    unsigned char* ldsrow = xs + r*(130*128);
    if (hv) {
      if (lane < 8) {   // zero pad col 0 (hf=0) / col 129 (hf=1)
        int s = hf ? (1032 + lane) : lane;
        uint4 zv; zv.x = 0; zv.y = 0; zv.z = 0; zv.w = 0;
        *reinterpret_cast<uint4*>(ldsrow + s*16) = zv;
      }
      const float* xrow = x + (((size_t)b*C_)*H_ + hh)*W_;   // + ci*HW_ + w
      int w0 = 2*lane, col0 = w0 + 1, col1 = w0 + 2;
      int g = lane >> 3;                                     // chunk rotation
#pragma unroll
      for (int i = 0; i < 4; ++i) {
        int chunk = (hf*4 + i + g) & 7;
        float2 v2[8];
#pragma unroll
        for (int j = 0; j < 8; ++j)
          v2[j] = *reinterpret_cast<const float2*>(xrow + (size_t)(chunk*8 + j)*HW_ + w0);
        uint4 o0, o1;
        unsigned short* s0 = reinterpret_cast<unsigned short*>(&o0);
        unsigned short* s1 = reinterpret_cast<unsigned short*>(&o1);
#pragma unroll
        for (int j = 0; j < 8; ++j) { s0[j] = f2bf(v2[j].x); s1[j] = f2bf(v2[j].y); }
        int a0 = col0*128 + (((chunk ^ col0) & 7) << 4);
        int a1 = col1*128 + (((chunk ^ col1) & 7) << 4);
        *reinterpret_cast<uint4*>(ldsrow + a0) = o0;
        *reinterpret_cast<uint4*>(ldsrow + a1) = o1;
      }
    } else {
      uint4 zv; zv.x = 0; zv.y = 0; zv.z = 0; zv.w = 0;
#pragma unroll
      for (int it = 0; it < 9; ++it) {   // zero half the row: 520 slots each
        int di = it*64 + lane;
        if (di < 520) *reinterpret_cast<uint4*>(ldsrow + (hf*520 + di)*16) = zv;
      }
    }
  }
  __syncthreads();

  int l15 = lane & 15, lhi = lane >> 4;
  int phr = v >> 2, pw0 = ((v >> 1) & 1)*64;
  int mt0 = (v & 1)*2;                       // co-tile base (co = mt0*16 .. +31)
  const unsigned short* wl = reinterpret_cast<const unsigned short*>(wlds);

  f32x4 acc[4][2];   // [pixel tile][co tile]
#pragma unroll
  for (int mp = 0; mp < 4; ++mp)
#pragma unroll
    for (int nc = 0; nc < 2; ++nc)
      acc[mp][nc] = (f32x4){0.f, 0.f, 0.f, 0.f};

  // ---- steady-state K-loop: pure LDS reads + MFMA, fully unrolled
#pragma unroll
  for (int t = 0; t < NT; ++t) {
    int kk = t >> 1, kh = kk/3, kw = kk - 3*kh, half = t & 1;
    int chunk = half*4 + lhi;
    short8 wf[2];
#pragma unroll
    for (int nc = 0; nc < 2; ++nc)
      wf[nc] = *reinterpret_cast<const short8*>(wl + ((t*4 + mt0 + nc)*64 + lane)*8);
    int rbase = (phr + kh)*130;
    short8 xa[4];
#pragma unroll
    for (int mp = 0; mp < 4; ++mp) {
      int col = pw0 + mp*16 + l15 + kw;
      xa[mp] = *reinterpret_cast<const short8*>(&xs[(rbase + col)*128 + (((chunk ^ col) & 7) << 4)]);
    }
#pragma unroll
    for (int mp = 0; mp < 4; ++mp)
#pragma unroll
      for (int nc = 0; nc < 2; ++nc)
        acc[mp][nc] = __builtin_amdgcn_mfma_f32_16x16x32_bf16(xa[mp], wf[nc], acc[mp][nc], 0, 0, 0);
  }

  // ---- epilogue: D row=(lane>>4)*4+i -> pixel (contiguous f32x4), col=lane&15 -> co
  int ph = h0 + phr;
#pragma unroll
  for (int nc = 0; nc < 2; ++nc) {
    int co = (mt0 + nc)*16 + l15;
    float* op = out + (((size_t)b*C_ + co)*H_ + ph)*W_;
#pragma unroll
    for (int mp = 0; mp < 4; ++mp) {
      int pix = pw0 + mp*16 + lhi*4;
      *reinterpret_cast<f32x4*>(op + pix) = acc[mp][nc];
    }
  }
}

__global__ void sentinel_k(float* out, int n) {
  int i = blockIdx.x*256 + threadIdx.x;
  if (i < n) out[i] = 1.0e6f;
}

extern "C" void kernel_launch(void* const* d_in, const int* in_sizes, int n_in,
                              void* d_out, int out_size, void* d_ws, size_t ws_size,
                              hipStream_t stream) {
  const float* x  = (const float*)d_in[0];
  const float* z  = (const float*)d_in[1];
  const float* gw = (const float*)d_in[2];
  const float* gb = (const float*)d_in[3];
  float* out = (float*)d_out;

  size_t wfrag_elems = (size_t)B_*IDXN;                   // bf16 elems
  size_t need = wfrag_elems*sizeof(unsigned short);
  if (ws_size < need) {
    sentinel_k<<<(out_size + 255)/256, 256, 0, stream>>>(out, out_size);
    return;
  }
  unsigned short* wfrag = (unsigned short*)d_ws;

  wgen_k <<<IDXN/128, 256, 0, stream>>>(z, gw, gb, wfrag);
  conv_k <<<B_*(H_/2), 512, 0, stream>>>(x, wfrag, out);
}

// Round 10
// 52.087 us; speedup vs baseline: 1.0820x; 1.0820x over previous
//
#include <hip/hip_runtime.h>
#include <hip/hip_bf16.h>

typedef __attribute__((ext_vector_type(4))) float f32x4;
typedef __attribute__((ext_vector_type(8))) short short8;

#define B_ 16
#define C_ 64
#define H_ 128
#define W_ 128
#define Z_ 128
#define HW_ (H_*W_)
#define IDXN (C_*C_*9)    // 36864 weight elements per sample
#define NT 18             // K=576 -> 18 MFMA k-steps of 32

__device__ __forceinline__ unsigned short f2bf(float f) {
  __hip_bfloat16 h = __float2bfloat16(f);
  return *reinterpret_cast<unsigned short*>(&h);
}

// ---------------- kernel 1: weight generation, pre-swizzled to MFMA fragment layout
__global__ __launch_bounds__(256) void wgen_k(
    const float* __restrict__ z, const float* __restrict__ gw,
    const float* __restrict__ gb, unsigned short* __restrict__ wfrag) {
  __shared__ __align__(16) float zs[B_*Z_];   // 8 KB
  int t = threadIdx.x;
#pragma unroll
  for (int i = 0; i < 8; ++i) zs[i*256 + t] = z[i*256 + t];
  __syncthreads();
  int lane = t & 63, bg = t >> 6;
  int b0 = bg*4;
  int idx0 = blockIdx.x*128 + lane;           // stream 0: idx0, stream 1: idx0+64
  float acc[4][2];
  float bv0 = gb[idx0], bv1 = gb[idx0 + 64];
#pragma unroll
  for (int bi = 0; bi < 4; ++bi) { acc[bi][0] = bv0; acc[bi][1] = bv1; }

  for (int z0 = 0; z0 < Z_; z0 += 4) {
    float ga[4], gbv[4];
#pragma unroll
    for (int zi = 0; zi < 4; ++zi) {
      ga[zi]  = gw[(size_t)(z0+zi)*IDXN + idx0];
      gbv[zi] = gw[(size_t)(z0+zi)*IDXN + idx0 + 64];
    }
#pragma unroll
    for (int bi = 0; bi < 4; ++bi) {
      f32x4 zq = *reinterpret_cast<const f32x4*>(&zs[(b0+bi)*Z_ + z0]);
      acc[bi][0] = fmaf(zq[0], ga[0], fmaf(zq[1], ga[1], fmaf(zq[2], ga[2], fmaf(zq[3], ga[3], acc[bi][0]))));
      acc[bi][1] = fmaf(zq[0], gbv[0], fmaf(zq[1], gbv[1], fmaf(zq[2], gbv[2], fmaf(zq[3], gbv[3], acc[bi][1]))));
    }
  }
#pragma unroll
  for (int ni = 0; ni < 2; ++ni) {
    int idx = idx0 + ni*64;
    int kw = idx % 3, r1 = idx/3;
    int kh = r1 % 3, r2 = r1/3;
    int ci = r2 & 63, co = r2 >> 6;
    int k = (kh*3 + kw)*C_ + ci;
    int ts = k >> 5, kin = k & 31;
    int lm = (co & 15) | ((kin >> 3) << 4);
    int j = kin & 7, m = co >> 4;
    int base = ((ts*4 + m)*64 + lm)*8 + j;
#pragma unroll
    for (int bi = 0; bi < 4; ++bi)
      wfrag[(size_t)(b0+bi)*(NT*4*64*8) + base] = f2bf(acc[bi][ni]);
  }
}

// ---------------- kernel 2 (fused): per-sample conv as MFMA implicit GEMM
// R5 shell (best known: 512 thr = 8 waves, 2-row block, 66560B LDS, 2 blocks/CU).
// ONLY change vs R5: epilogue routes accs through LDS so every global store
// instruction writes 1024 B CONTIGUOUS (one co-plane 2-row run per wave-instr)
// instead of 16 x 64 B segments scattered across 16 co planes.
// LDS: xs[4 rows][130 cols][8 chunk-slots][16B]; slot s at col holds chunk s^(col&7)
__global__ __launch_bounds__(512, 4) void conv_k(
    const float* __restrict__ x,
    const unsigned short* __restrict__ wfrag,
    float* __restrict__ out) {
  __shared__ __align__(16) unsigned char xs[4*130*128];   // 66560 B; reused as obuf[64][260] f32
  int orig = blockIdx.x;
  int blk = (orig & 7)*128 + (orig >> 3);   // bijective XCD swizzle: 1024 = 8*128
  int b = blk >> 6;
  int h0 = (blk & 63)*2;
  int tid = threadIdx.x;
  int v = tid >> 6, lane = tid & 63;

  // ---- stage 4 halo rows (h0-1..h0+2); wave v stages (row v>>1, chunk-half v&1)
  {
    int r = v >> 1, hf = v & 1;
    int hh = h0 - 1 + r;
    bool hv = (hh >= 0) & (hh < H_);
    unsigned char* ldsrow = xs + r*(130*128);
    if (hv) {
      if (lane < 8) {   // zero pad col 0 (hf=0) / col 129 (hf=1)
        int s = hf ? (1032 + lane) : lane;
        uint4 zv; zv.x = 0; zv.y = 0; zv.z = 0; zv.w = 0;
        *reinterpret_cast<uint4*>(ldsrow + s*16) = zv;
      }
      const float* xrow = x + (((size_t)b*C_)*H_ + hh)*W_;   // + ci*(H_*W_) + w
      int w0 = 2*lane, col0 = w0 + 1, col1 = w0 + 2;
      int g = lane >> 3;                                     // chunk rotation
#pragma unroll
      for (int i = 0; i < 4; ++i) {
        int chunk = (hf*4 + i + g) & 7;
        float2 v2[8];
#pragma unroll
        for (int j = 0; j < 8; ++j)
          v2[j] = *reinterpret_cast<const float2*>(xrow + (size_t)(chunk*8 + j)*HW_ + w0);
        uint4 o0, o1;
        unsigned short* s0 = reinterpret_cast<unsigned short*>(&o0);
        unsigned short* s1 = reinterpret_cast<unsigned short*>(&o1);
#pragma unroll
        for (int j = 0; j < 8; ++j) { s0[j] = f2bf(v2[j].x); s1[j] = f2bf(v2[j].y); }
        int a0 = col0*128 + (((chunk ^ col0) & 7) << 4);
        int a1 = col1*128 + (((chunk ^ col1) & 7) << 4);
        *reinterpret_cast<uint4*>(ldsrow + a0) = o0;
        *reinterpret_cast<uint4*>(ldsrow + a1) = o1;
      }
    } else {
      uint4 zv; zv.x = 0; zv.y = 0; zv.z = 0; zv.w = 0;
#pragma unroll
      for (int it = 0; it < 9; ++it) {   // zero half the row: 520 slots each
        int di = it*64 + lane;
        if (di < 520) *reinterpret_cast<uint4*>(ldsrow + (hf*520 + di)*16) = zv;
      }
    }
  }

  int l15 = lane & 15, lhi = lane >> 4;
  int phr = v >> 2, pw0 = ((v >> 1) & 1)*64;
  int mt0 = (v & 1)*2;                       // co-tile base (co = mt0*16 .. +31)
  const unsigned short* wb = wfrag + (size_t)b*(NT*4*64*8);

  // prefetch t=0 weight tiles above the barrier (VGPR-dest, no LDS dep)
  short8 wf0 = *reinterpret_cast<const short8*>(wb + (((mt0 + 0)*64 + lane)*8));
  short8 wf1 = *reinterpret_cast<const short8*>(wb + (((mt0 + 1)*64 + lane)*8));

  __syncthreads();

  f32x4 acc[4][2];   // [pixel tile][co tile]
#pragma unroll
  for (int mp = 0; mp < 4; ++mp)
#pragma unroll
    for (int nc = 0; nc < 2; ++nc)
      acc[mp][nc] = (f32x4){0.f, 0.f, 0.f, 0.f};

#pragma unroll
  for (int t = 0; t < NT; ++t) {
    int kk = t >> 1, kh = kk/3, kw = kk - 3*kh, half = t & 1;
    short8 nf0, nf1;
    if (t + 1 < NT) {                        // prefetch next weight tiles
      nf0 = *reinterpret_cast<const short8*>(wb + ((((t+1)*4 + mt0 + 0)*64 + lane)*8));
      nf1 = *reinterpret_cast<const short8*>(wb + ((((t+1)*4 + mt0 + 1)*64 + lane)*8));
    }
    int chunk = half*4 + lhi;                // ci0>>3
    short8 xa[4];
#pragma unroll
    for (int mp = 0; mp < 4; ++mp) {         // A operand: pixels from LDS
      int col = pw0 + mp*16 + l15 + kw;      // padded col = pix + kw, in [0,129]
      int addr = ((phr + kh)*130 + col)*128 + (((chunk ^ col) & 7) << 4);
      xa[mp] = *reinterpret_cast<const short8*>(&xs[addr]);
    }
#pragma unroll
    for (int mp = 0; mp < 4; ++mp) {
      acc[mp][0] = __builtin_amdgcn_mfma_f32_16x16x32_bf16(xa[mp], wf0, acc[mp][0], 0, 0, 0);
      acc[mp][1] = __builtin_amdgcn_mfma_f32_16x16x32_bf16(xa[mp], wf1, acc[mp][1], 0, 0, 0);
    }
    wf0 = nf0; wf1 = nf1;
  }

  // ---- epilogue v2: route through LDS, then 1024-B-contiguous stores
  __syncthreads();                           // xs dead (all waves past K-loop)
  float* obuf = reinterpret_cast<float*>(xs);  // obuf[co][260] f32; uses 64*260*4 = 66560 B
  // D row=(lane>>4)*4+i -> pixel (f32x4 contiguous), col=lane&15 -> co
#pragma unroll
  for (int nc = 0; nc < 2; ++nc) {
    int co = (mt0 + nc)*16 + l15;
#pragma unroll
    for (int mp = 0; mp < 4; ++mp) {
      int px = pw0 + mp*16 + lhi*4;
      *reinterpret_cast<f32x4*>(&obuf[co*260 + phr*128 + px]) = acc[mp][nc];
    }
  }
  __syncthreads();
  // each wave-instr: one co plane, 64 lanes x 16 B = 1024 B contiguous (2 rows)
  {
    float* ob = out + ((size_t)b*C_)*HW_ + (size_t)h0*W_;   // + co*HW_ + row*W_ + w
#pragma unroll
    for (int i = 0; i < 8; ++i) {
      int co = i*8 + v;
      f32x4 val = *reinterpret_cast<const f32x4*>(&obuf[co*260 + lane*4]);
      *reinterpret_cast<f32x4*>(ob + (size_t)co*HW_ + lane*4) = val;
    }
  }
}

__global__ void sentinel_k(float* out, int n) {
  int i = blockIdx.x*256 + threadIdx.x;
  if (i < n) out[i] = 1.0e6f;
}

extern "C" void kernel_launch(void* const* d_in, const int* in_sizes, int n_in,
                              void* d_out, int out_size, void* d_ws, size_t ws_size,
                              hipStream_t stream) {
  const float* x  = (const float*)d_in[0];
  const float* z  = (const float*)d_in[1];
  const float* gw = (const float*)d_in[2];
  const float* gb = (const float*)d_in[3];
  float* out = (float*)d_out;

  size_t wfrag_elems = (size_t)B_*IDXN;                   // bf16 elems
  size_t need = wfrag_elems*sizeof(unsigned short);
  if (ws_size < need) {
    sentinel_k<<<(out_size + 255)/256, 256, 0, stream>>>(out, out_size);
    return;
  }
  unsigned short* wfrag = (unsigned short*)d_ws;

  wgen_k <<<IDXN/128, 256, 0, stream>>>(z, gw, gb, wfrag);
  conv_k <<<B_*(H_/2), 512, 0, stream>>>(x, wfrag, out);
}